// Round 13
// baseline (974.887 us; speedup 1.0000x reference)
//
#include <hip/hip_runtime.h>
#include <hip/hip_bf16.h>

#define FCD 2048
#define VEMBD 512
#define WEMBD 512
#define HD 512
#define AD 256
#define TVD 32
#define TCD 20
#define BCD 16
#define RPD 32
#define BD 512     // BCD*RPD
#define GLOVED 300

typedef __attribute__((ext_vector_type(8))) short short8v;
typedef __attribute__((ext_vector_type(4))) float f32x4;

__device__ __forceinline__ float sigf(float x) { return 1.0f / (1.0f + __expf(-x)); }
__device__ __forceinline__ float tanhfast(float x) {
    float e = __expf(2.0f * x);
    return 1.0f - 2.0f / (e + 1.0f);
}
__device__ __forceinline__ unsigned short f2bf(float x) {
    union { __hip_bfloat16 h; unsigned short u; } v;
    v.h = __float2bfloat16(x);
    return v.u;
}
__device__ __forceinline__ float b2f(unsigned short u) {
    union { unsigned int i; float f; } v;
    v.i = ((unsigned int)u) << 16;
    return v.f;
}

// ---------------------------------------------------------------------------
// fp32 -> bf16 elementwise convert
// ---------------------------------------------------------------------------
__launch_bounds__(256)
__global__ void conv_f2b_kernel(const float* __restrict__ src,
                                unsigned short* __restrict__ dst, int n4) {
    for (int i = blockIdx.x * 256 + threadIdx.x; i < n4; i += gridDim.x * 256) {
        const float4 v = ((const float4*)src)[i];
        ushort4 o;
        o.x = f2bf(v.x); o.y = f2bf(v.y); o.z = f2bf(v.z); o.w = f2bf(v.w);
        ((ushort4*)dst)[i] = o;
    }
}

// Permuted+concatenated gate weights: Wcat[g'][0:512]=Wih[g], [512:1024]=Whh[g]
// g' = (hc>>4)*64 + q*16 + (hc&15), g = q*512 + hc. bf16 out.
__launch_bounds__(256)
__global__ void conv_wcat_perm_kernel(const float* __restrict__ Wih,
                                      const float* __restrict__ Whh,
                                      unsigned short* __restrict__ Wcat) {
    const int gp = blockIdx.x;
    const int q = (gp >> 4) & 3;
    const int hc = (gp >> 6) * 16 + (gp & 15);
    const long g = (long)(q * 512 + hc);
    for (int k = threadIdx.x; k < 512; k += 256) {
        Wcat[(long)gp * 1024 + k]       = f2bf(Wih[g * 512 + k]);
        Wcat[(long)gp * 1024 + 512 + k] = f2bf(Whh[g * 512 + k]);
    }
}

__launch_bounds__(256)
__global__ void conv_bsum_kernel(const float* __restrict__ bih,
                                 const float* __restrict__ bhh,
                                 float* __restrict__ bsum) {
    const int gp = blockIdx.x * 256 + threadIdx.x;
    if (gp < 2048) {
        const int q = (gp >> 4) & 3;
        const int hc = (gp >> 6) * 16 + (gp & 15);
        const int g = q * 512 + hc;
        bsum[gp] = bih[g] + bhh[g];
    }
}

// ---------------------------------------------------------------------------
// MFMA bf16 GEMM, 128x128 tile, BK=64, register-prefetch staging.
// Grid: x = m-tiles (fastest), y = n-tiles.
// ---------------------------------------------------------------------------
template<int AF32, int OBF>
__launch_bounds__(256)
__global__ void mfma_gemm128(const void* __restrict__ A,
                             const unsigned short* __restrict__ Bw,
                             const float* __restrict__ bias,
                             void* __restrict__ Cout,
                             int M, int N, int K)
{
    __shared__ unsigned short As[128][72];
    __shared__ unsigned short Bs[128][72];
    const int m0 = blockIdx.x * 128;
    const int n0 = blockIdx.y * 128;
    const int tid = threadIdx.x;
    const int lane = tid & 63;
    const int wid = tid >> 6;
    const int wm = (wid >> 1) * 64;
    const int wn = (wid & 1) * 64;
    const int lrow = lane & 15;
    const int lko = (lane >> 4) * 8;
    const int sr = tid >> 1;
    const int sc = (tid & 1) * 32;

    f32x4 acc[4][4] = {};

    const float* Arow_f = (const float*)A + (long)(m0 + sr) * K;
    const unsigned short* Arow_b = (const unsigned short*)A + (long)(m0 + sr) * K;
    const unsigned short* Brow = Bw + (long)(n0 + sr) * K;

    if (AF32) {
#pragma unroll
        for (int i = 0; i < 8; i++) {
            const float4 v = *(const float4*)(Arow_f + sc + i * 4);
            unsigned short* d = &As[sr][sc + i * 4];
            d[0] = f2bf(v.x); d[1] = f2bf(v.y); d[2] = f2bf(v.z); d[3] = f2bf(v.w);
        }
    } else {
#pragma unroll
        for (int i = 0; i < 4; i++)
            *(short8v*)&As[sr][sc + i * 8] = *(const short8v*)(Arow_b + sc + i * 8);
    }
#pragma unroll
    for (int i = 0; i < 4; i++)
        *(short8v*)&Bs[sr][sc + i * 8] = *(const short8v*)(Brow + sc + i * 8);
    __syncthreads();

    const int nc = K >> 6;
    float4 paf[8];
    short8v pab[4], pb[4];
    for (int c = 0; c < nc; c++) {
        if (c < nc - 1) {
            const int k0 = (c + 1) * 64;
            if (AF32) {
#pragma unroll
                for (int i = 0; i < 8; i++)
                    paf[i] = *(const float4*)(Arow_f + k0 + sc + i * 4);
            } else {
#pragma unroll
                for (int i = 0; i < 4; i++)
                    pab[i] = *(const short8v*)(Arow_b + k0 + sc + i * 8);
            }
#pragma unroll
            for (int i = 0; i < 4; i++)
                pb[i] = *(const short8v*)(Brow + k0 + sc + i * 8);
        }
#pragma unroll
        for (int kk = 0; kk < 2; kk++) {
            short8v a[4], b[4];
#pragma unroll
            for (int mi = 0; mi < 4; mi++)
                a[mi] = *(const short8v*)&As[wm + mi * 16 + lrow][kk * 32 + lko];
#pragma unroll
            for (int ni = 0; ni < 4; ni++)
                b[ni] = *(const short8v*)&Bs[wn + ni * 16 + lrow][kk * 32 + lko];
#pragma unroll
            for (int mi = 0; mi < 4; mi++)
#pragma unroll
                for (int ni = 0; ni < 4; ni++)
                    acc[mi][ni] = __builtin_amdgcn_mfma_f32_16x16x32_bf16(
                        a[mi], b[ni], acc[mi][ni], 0, 0, 0);
        }
        __syncthreads();
        if (c < nc - 1) {
            if (AF32) {
#pragma unroll
                for (int i = 0; i < 8; i++) {
                    unsigned short* d = &As[sr][sc + i * 4];
                    d[0] = f2bf(paf[i].x); d[1] = f2bf(paf[i].y);
                    d[2] = f2bf(paf[i].z); d[3] = f2bf(paf[i].w);
                }
            } else {
#pragma unroll
                for (int i = 0; i < 4; i++)
                    *(short8v*)&As[sr][sc + i * 8] = pab[i];
            }
#pragma unroll
            for (int i = 0; i < 4; i++)
                *(short8v*)&Bs[sr][sc + i * 8] = pb[i];
            __syncthreads();
        }
    }

    const int rbase = (lane >> 4) * 4;
#pragma unroll
    for (int ni = 0; ni < 4; ni++) {
        const int col = n0 + wn + ni * 16 + lrow;
        const float bv = bias[col];
#pragma unroll
        for (int mi = 0; mi < 4; mi++) {
#pragma unroll
            for (int j = 0; j < 4; j++) {
                const long row = m0 + wm + mi * 16 + rbase + j;
                const float val = acc[mi][ni][j] + bv;
                if (OBF) ((unsigned short*)Cout)[row * N + col] = f2bf(val);
                else     ((float*)Cout)[row * N + col] = val;
            }
        }
    }
}

// ---------------------------------------------------------------------------
// Fused LSTM step, 256 threads, 21.3 KB LDS, 4 blocks/CU occupancy.
// Blocks 0..1023: vid step, tile = 16 batch x 64 g'. BK=128 (8 chunks),
//   1-deep register prefetch. Wave w owns gate q=w for all 16 batches
//   (1 MFMA per k-slice); waves 1-3 hand their gate to wave 0 via a 3 KB
//   LDS exchange. Per-output k-accumulation order identical to R10 ->
//   identical numerics.
// Blocks 1024..1055 (t<TC): caption fp32 step (proven body).
// ---------------------------------------------------------------------------
__launch_bounds__(256, 2)
__global__ void step_fused(const unsigned short* __restrict__ vx,   // [B*TV][512] bf16
                           const unsigned short* __restrict__ h_in, // [B][512] bf16
                           unsigned short* __restrict__ h_out,      // [B][512] bf16
                           const unsigned short* __restrict__ Wcat, // [2048][1024] bf16
                           const float* __restrict__ bsum,          // [2048]
                           float* __restrict__ c_state,             // [B][512] f32
                           unsigned short* __restrict__ vid_h,      // [B*TV][512] bf16
                           int t,
                           const float* __restrict__ xg,            // cap
                           const float* __restrict__ Whh_c,
                           const float* __restrict__ bhh_c,
                           const float* __restrict__ hc_in,
                           float* __restrict__ hc_out,
                           float* __restrict__ cap_cst,
                           float* __restrict__ cap_h)
{
    __shared__ __align__(16) unsigned char smem[21760];
    const int bx = blockIdx.x;
    const int tid = threadIdx.x;

    if (bx >= 1024) {
        // ---------------- caption step (fp32, 256 threads) ----------------
        const int h0 = (bx - 1024) * 16;
        float* Wsc = (float*)smem;              // [64][68] = 17408 B
        float* Hshc = (float*)(smem + 17408);   // [16][68] = 4352 B
        const int tx = tid & 15;
        const int ty = tid >> 4;
        const int lrow2 = tid >> 2;
        const int lq = tid & 3;
        float acc4[4] = {};

        for (int k0 = 0; k0 < 512; k0 += 64) {
            {
                const int q = lrow2 >> 4;
                const int hcc = lrow2 & 15;
                const float* src = Whh_c + (long)(q * 512 + h0 + hcc) * 512 + k0 + lq * 16;
                const int col = hcc * 4 + q;
#pragma unroll
                for (int j = 0; j < 4; j++) {
                    const float4 v = *(const float4*)(src + j * 4);
                    Wsc[(lq * 16 + j * 4 + 0) * 68 + col] = v.x;
                    Wsc[(lq * 16 + j * 4 + 1) * 68 + col] = v.y;
                    Wsc[(lq * 16 + j * 4 + 2) * 68 + col] = v.z;
                    Wsc[(lq * 16 + j * 4 + 3) * 68 + col] = v.w;
                }
            }
            {
                const int lb = tid >> 4;
                const int lk4 = (tid & 15) * 4;
                *(float4*)&Hshc[lb * 68 + lk4] = *(const float4*)(hc_in + (long)lb * 512 + k0 + lk4);
            }
            __syncthreads();
#pragma unroll
            for (int kq = 0; kq < 16; kq++) {
                const float4 h4 = *(const float4*)&Hshc[ty * 68 + kq * 4];
                const float4 w0 = *(const float4*)&Wsc[(kq * 4 + 0) * 68 + tx * 4];
                const float4 w1 = *(const float4*)&Wsc[(kq * 4 + 1) * 68 + tx * 4];
                const float4 w2 = *(const float4*)&Wsc[(kq * 4 + 2) * 68 + tx * 4];
                const float4 w3 = *(const float4*)&Wsc[(kq * 4 + 3) * 68 + tx * 4];
                acc4[0] += h4.x * w0.x + h4.y * w1.x + h4.z * w2.x + h4.w * w3.x;
                acc4[1] += h4.x * w0.y + h4.y * w1.y + h4.z * w2.y + h4.w * w3.y;
                acc4[2] += h4.x * w0.z + h4.y * w1.z + h4.z * w2.z + h4.w * w3.z;
                acc4[3] += h4.x * w0.w + h4.y * w1.w + h4.z * w2.w + h4.w * w3.w;
            }
            __syncthreads();
        }
        const int hc = h0 + tx;
        const long xrow = (long)(ty * TCD + t) * 2048;
        const float gi = acc4[0] + xg[xrow + hc]        + bhh_c[hc];
        const float gf = acc4[1] + xg[xrow + 512 + hc]  + bhh_c[512 + hc];
        const float gg = acc4[2] + xg[xrow + 1024 + hc] + bhh_c[1024 + hc];
        const float go = acc4[3] + xg[xrow + 1536 + hc] + bhh_c[1536 + hc];
        const float c_old = cap_cst[(long)ty * 512 + hc];
        const float ii = sigf(gi), ff = sigf(gf), g2 = tanhfast(gg), oo = sigf(go);
        const float c = ff * c_old + ii * g2;
        const float h = oo * tanhfast(c);
        cap_cst[(long)ty * 512 + hc] = c;
        hc_out[(long)ty * 512 + hc] = h;
        cap_h[(long)(ty * TCD + t) * 512 + hc] = h;
        return;
    }

    // ---------------- video step (16 batch x 64 g', BK=128, 8 chunks) ------
    const int n0 = (bx & 31) * 64;    // g' base (32 tiles)
    const int b0 = (bx >> 5) * 16;    // batch base (32 tiles)
    const int lane = tid & 63;
    const int w = tid >> 6;           // wave = gate q
    const int lrow = lane & 15;
    const int lko = (lane >> 4) * 8;
    const int sra = tid >> 4;         // A staging row 0..15
    const int sca = (tid & 15) * 8;   // A staging col base (8 elems)
    const int srw = tid >> 2;         // W staging row 0..63
    const int scw = (tid & 3) * 32;   // W staging col base (32 elems)

    unsigned short* As = (unsigned short*)smem;           // [16][136] = 4352 B
    unsigned short* Ws = (unsigned short*)(smem + 4352);  // [64][136] = 17408 B
    float* red = (float*)smem;        // [3][16][16] f32 = 3072 B (aliases As)

    const unsigned short* arow_vx = vx + ((long)(b0 + sra) * TVD + t) * 512;
    const unsigned short* arow_h  = h_in + (long)(b0 + sra) * 512;
    const unsigned short* wrow    = Wcat + (long)(n0 + srw) * 1024;

    f32x4 acc = {};

    // stage chunk 0 (k 0..127, vx side)
    *(short8v*)&As[sra * 136 + sca] = *(const short8v*)(arow_vx + sca);
#pragma unroll
    for (int i = 0; i < 4; i++)
        *(short8v*)&Ws[srw * 136 + scw + i * 8] = *(const short8v*)(wrow + scw + i * 8);
    __syncthreads();

    short8v pa, pw[4];
    for (int c = 0; c < 8; c++) {
        if (c < 7) {
            const int k0 = (c + 1) * 128;
            const unsigned short* ap = (k0 < 512) ? (arow_vx + k0) : (arow_h + (k0 - 512));
            pa = *(const short8v*)(ap + sca);
#pragma unroll
            for (int i = 0; i < 4; i++)
                pw[i] = *(const short8v*)(wrow + k0 + scw + i * 8);
        }
#pragma unroll
        for (int kk = 0; kk < 4; kk++) {
            const short8v a = *(const short8v*)&As[lrow * 136 + kk * 32 + lko];
            const short8v b = *(const short8v*)&Ws[(w * 16 + lrow) * 136 + kk * 32 + lko];
            acc = __builtin_amdgcn_mfma_f32_16x16x32_bf16(a, b, acc, 0, 0, 0);
        }
        __syncthreads();
        if (c < 7) {
            *(short8v*)&As[sra * 136 + sca] = pa;
#pragma unroll
            for (int i = 0; i < 4; i++)
                *(short8v*)&Ws[srw * 136 + scw + i * 8] = pw[i];
            __syncthreads();
        }
    }

    // gate exchange: waves 1..3 (q1,q2,q3) -> LDS; wave 0 does cell update
    const int rbase = (lane >> 4) * 4;
    if (w >= 1) {
#pragma unroll
        for (int j = 0; j < 4; j++)
            red[(w - 1) * 256 + (rbase + j) * 16 + lrow] = acc[j];
    }
    __syncthreads();
    if (w == 0) {
        const int hc = (n0 >> 2) + lrow;
        const float bs0 = bsum[n0 + lrow];
        const float bs1 = bsum[n0 + 16 + lrow];
        const float bs2 = bsum[n0 + 32 + lrow];
        const float bs3 = bsum[n0 + 48 + lrow];
#pragma unroll
        for (int j = 0; j < 4; j++) {
            const int blocal = rbase + j;
            const long b = b0 + blocal;
            const float gi = acc[j] + bs0;
            const float gf = red[0 * 256 + blocal * 16 + lrow] + bs1;
            const float gg = red[1 * 256 + blocal * 16 + lrow] + bs2;
            const float go = red[2 * 256 + blocal * 16 + lrow] + bs3;
            const float c_old = c_state[b * 512 + hc];
            const float ii = sigf(gi), ff = sigf(gf), g2 = tanhfast(gg), oo = sigf(go);
            const float cn = ff * c_old + ii * g2;
            const float h = oo * tanhfast(cn);
            c_state[b * 512 + hc] = cn;
            h_out[b * 512 + hc] = f2bf(h);
            vid_h[(b * TVD + t) * 512 + hc] = f2bf(h);
        }
    }
}

// ---------------------------------------------------------------------------
// Generic fp32 tiled GEMM (cap front path + c_lin)
// ---------------------------------------------------------------------------
__launch_bounds__(256)
__global__ void gemm_bias_kernel(const float* __restrict__ A,
                                 const float* __restrict__ Bw,
                                 const float* __restrict__ bias,
                                 float* __restrict__ C,
                                 int M, int N, int K) {
    __shared__ float As[16][68];
    __shared__ float Bs[16][68];
    const int n0 = blockIdx.x * 64;
    const int m0 = blockIdx.y * 64;
    const int tid = threadIdx.x;
    const int tx = tid & 15;
    const int ty = tid >> 4;
    const int lrow = tid >> 2;
    const int lk4 = (tid & 3) * 4;

    float acc[4][4] = {};

    for (int k0 = 0; k0 < K; k0 += 16) {
        {
            const float* src = A + (long)(m0 + lrow) * K + k0 + lk4;
            float4 v;
            if (k0 + 16 <= K) v = *(const float4*)src;
            else {
                v.x = (k0 + lk4 + 0 < K) ? src[0] : 0.f;
                v.y = (k0 + lk4 + 1 < K) ? src[1] : 0.f;
                v.z = (k0 + lk4 + 2 < K) ? src[2] : 0.f;
                v.w = (k0 + lk4 + 3 < K) ? src[3] : 0.f;
            }
            As[lk4 + 0][lrow] = v.x; As[lk4 + 1][lrow] = v.y;
            As[lk4 + 2][lrow] = v.z; As[lk4 + 3][lrow] = v.w;
        }
        {
            const float* src = Bw + (long)(n0 + lrow) * K + k0 + lk4;
            float4 v;
            if (k0 + 16 <= K) v = *(const float4*)src;
            else {
                v.x = (k0 + lk4 + 0 < K) ? src[0] : 0.f;
                v.y = (k0 + lk4 + 1 < K) ? src[1] : 0.f;
                v.z = (k0 + lk4 + 2 < K) ? src[2] : 0.f;
                v.w = (k0 + lk4 + 3 < K) ? src[3] : 0.f;
            }
            Bs[lk4 + 0][lrow] = v.x; Bs[lk4 + 1][lrow] = v.y;
            Bs[lk4 + 2][lrow] = v.z; Bs[lk4 + 3][lrow] = v.w;
        }
        __syncthreads();
#pragma unroll
        for (int kk = 0; kk < 16; kk++) {
            const float4 av = *(const float4*)&As[kk][ty * 4];
            const float4 bv = *(const float4*)&Bs[kk][tx * 4];
            acc[0][0] += av.x * bv.x; acc[0][1] += av.x * bv.y; acc[0][2] += av.x * bv.z; acc[0][3] += av.x * bv.w;
            acc[1][0] += av.y * bv.x; acc[1][1] += av.y * bv.y; acc[1][2] += av.y * bv.z; acc[1][3] += av.y * bv.w;
            acc[2][0] += av.z * bv.x; acc[2][1] += av.z * bv.y; acc[2][2] += av.z * bv.z; acc[2][3] += av.z * bv.w;
            acc[3][0] += av.w * bv.x; acc[3][1] += av.w * bv.y; acc[3][2] += av.w * bv.z; acc[3][3] += av.w * bv.w;
        }
        __syncthreads();
    }

    const float b0v = bias[n0 + tx * 4 + 0];
    const float b1v = bias[n0 + tx * 4 + 1];
    const float b2v = bias[n0 + tx * 4 + 2];
    const float b3v = bias[n0 + tx * 4 + 3];
#pragma unroll
    for (int i = 0; i < 4; i++) {
        float* dst = C + (long)(m0 + ty * 4 + i) * N + n0 + tx * 4;
        dst[0] = acc[i][0] + b0v;
        dst[1] = acc[i][1] + b1v;
        dst[2] = acc[i][2] + b2v;
        dst[3] = acc[i][3] + b3v;
    }
}

// ---------------------------------------------------------------------------
// Attention + cap_ftr fused, shuffle-free: one block per (bc,rp).
// ---------------------------------------------------------------------------
#define PFL 258
__launch_bounds__(256, 2)
__global__ void attn_kernel(const float* __restrict__ v_lin,
                            const float* __restrict__ c_lin,
                            const float* __restrict__ W_att,
                            const float* __restrict__ b_att,
                            const int* __restrict__ cap_len,
                            const float* __restrict__ cap_h,
                            float* __restrict__ out2)
{
    const int br = blockIdx.x;
    const int bc = br >> 5;
    const int tid = threadIdx.x;
    __shared__ float cl[TCD][PFL];
    __shared__ float vl[TVD][PFL];
    __shared__ float wa[AD];
    __shared__ float sl[TVD][TCD];
    __shared__ float wsum[TCD];

    {
        const float* csrc = c_lin + (long)bc * TCD * AD;
        for (int idx = tid; idx < TCD * 128; idx += 256) {
            const int row = idx >> 7, c2 = (idx & 127) * 2;
            *(float2*)&cl[row][c2] = *(const float2*)(csrc + row * AD + c2);
        }
        const float* vsrc = v_lin + (long)br * TVD * AD;
        for (int idx = tid; idx < TVD * 128; idx += 256) {
            const int row = idx >> 7, c2 = (idx & 127) * 2;
            *(float2*)&vl[row][c2] = *(const float2*)(vsrc + row * AD + c2);
        }
        wa[tid] = W_att[tid];
    }
    const float batt = b_att[0];
    __syncthreads();

    {
        const int v = tid & 31;
        const int tg = tid >> 5;        // 0..7
        const int t0 = tg, t1 = tg + 8, t2 = tg + 16;
        const bool ok2 = (t2 < TCD);
        const int t2c = ok2 ? t2 : 0;
        float s0 = 0.f, s1 = 0.f, s2 = 0.f;
#pragma unroll 4
        for (int i = 0; i < 128; i++) {
            const float2 w2 = *(const float2*)&wa[2 * i];
            const float2 vv = *(const float2*)&vl[v][2 * i];
            const float2 c0 = *(const float2*)&cl[t0][2 * i];
            const float2 c1 = *(const float2*)&cl[t1][2 * i];
            const float2 c2 = *(const float2*)&cl[t2c][2 * i];
            s0 += tanhfast(vv.x + c0.x) * w2.x + tanhfast(vv.y + c0.y) * w2.y;
            s1 += tanhfast(vv.x + c1.x) * w2.x + tanhfast(vv.y + c1.y) * w2.y;
            s2 += tanhfast(vv.x + c2.x) * w2.x + tanhfast(vv.y + c2.y) * w2.y;
        }
        sl[v][t0] = s0 + batt;
        sl[v][t1] = s1 + batt;
        if (ok2) sl[v][t2] = s2 + batt;
    }
    __syncthreads();

    int L = cap_len[bc];
    if (L < 1) L = 1;
    if (tid < TVD) {
        const int v = tid;
        float m = -1e30f;
        for (int t = 0; t < TCD; t++)
            if (t < L) m = fmaxf(m, sl[v][t]);
        float sum = 0.f;
        for (int t = 0; t < TCD; t++)
            if (t < L) sum += __expf(sl[v][t] - m);
        const float inv = 1.f / sum;
        for (int t = 0; t < TCD; t++)
            sl[v][t] = (t < L) ? __expf(sl[v][t] - m) * inv : 0.f;
    }
    __syncthreads();
    if (tid < TCD) {
        float s = 0.f;
        for (int v = 0; v < TVD; v++) s += sl[v][tid];
        wsum[tid] = s * (1.0f / TVD);
    }
    __syncthreads();

    const float* chb = cap_h + (long)bc * TCD * HD;
#pragma unroll
    for (int r = 0; r < 2; r++) {
        const int h = r * 256 + tid;
        float s = 0.f;
#pragma unroll
        for (int t = 0; t < TCD; t++)
            s += wsum[t] * chb[t * HD + h];
        out2[(long)br * HD + h] = s;
    }
}

// vid_mean from bf16 vid_h
__launch_bounds__(256)
__global__ void vidmean_bf_kernel(const unsigned short* __restrict__ vid_h,
                                  float* __restrict__ out1)
{
    const int idx = blockIdx.x * 256 + threadIdx.x;   // 0..32767
    const int b = idx >> 6;
    const int h8 = (idx & 63) * 8;
    float s[8] = {};
    for (int t = 0; t < TVD; t++) {
        const short8v v = *(const short8v*)(vid_h + ((long)b * TVD + t) * 512 + h8);
#pragma unroll
        for (int j = 0; j < 8; j++) s[j] += b2f((unsigned short)v[j]);
    }
#pragma unroll
    for (int j = 0; j < 8; j++)
        out1[(long)b * 512 + h8 + j] = s[j] * (1.0f / TVD);
}

extern "C" void kernel_launch(void* const* d_in, const int* in_sizes, int n_in,
                              void* d_out, int out_size, void* d_ws, size_t ws_size,
                              hipStream_t stream) {
    const float* video_fc      = (const float*)d_in[0];
    const float* video_caption = (const float*)d_in[1];
    const int*   cap_len       = (const int*)d_in[2];
    const float* W_vemb = (const float*)d_in[3];
    const float* b_vemb = (const float*)d_in[4];
    const float* W_wemb = (const float*)d_in[5];
    const float* b_wemb = (const float*)d_in[6];
    const float* Wih_v  = (const float*)d_in[7];
    const float* Whh_v  = (const float*)d_in[8];
    const float* bih_v  = (const float*)d_in[9];
    const float* bhh_v  = (const float*)d_in[10];
    const float* Wih_c  = (const float*)d_in[11];
    const float* Whh_c  = (const float*)d_in[12];
    const float* bih_c  = (const float*)d_in[13];
    const float* bhh_c  = (const float*)d_in[14];
    const float* W_vid  = (const float*)d_in[15];
    const float* b_vid  = (const float*)d_in[16];
    const float* W_sen  = (const float*)d_in[17];
    const float* b_sen  = (const float*)d_in[18];
    const float* W_att  = (const float*)d_in[19];
    const float* b_att  = (const float*)d_in[20];

    float* out1 = (float*)d_out;            // vid_mean
    float* out2 = out1 + BD * HD;           // cap_ftr_mean

    float* ws = (float*)d_ws;
    size_t off = 0;
    auto alloc = [&](size_t nfloats) {
        float* p = ws + off;
        off += (nfloats + 63) & ~(size_t)63;
        return p;
    };
    unsigned short* vidx_bf = (unsigned short*)alloc((size_t)BD * TVD * VEMBD / 2);
    unsigned short* vidh_bf = (unsigned short*)alloc((size_t)BD * TVD * HD / 2);
    unsigned short* h_bf_a  = (unsigned short*)alloc((size_t)BD * HD / 2);
    unsigned short* h_bf_b  = (unsigned short*)alloc((size_t)BD * HD / 2);
    float* c_st    = alloc((size_t)BD * HD);
    float* v_lin   = alloc((size_t)BD * TVD * AD);
    unsigned short* Wvemb_bf = (unsigned short*)alloc((size_t)VEMBD * FCD / 2);
    unsigned short* Wvid_bf  = (unsigned short*)alloc((size_t)AD * HD / 2);
    unsigned short* Wcat_bf  = (unsigned short*)alloc((size_t)2048 * 1024 / 2);
    float* bsum    = alloc(2048);
    float* cap_x   = alloc((size_t)BCD * TCD * WEMBD);
    float* xg_c    = alloc((size_t)BCD * TCD * 4 * HD);
    float* cap_h   = alloc((size_t)BCD * TCD * HD);
    float* c_lin   = alloc((size_t)BCD * TCD * AD);
    float* cap_ha  = alloc((size_t)BCD * HD);
    float* cap_hb  = alloc((size_t)BCD * HD);
    float* cap_cst = alloc((size_t)BCD * HD);
    // big optional buffer last: bf16 copy of video_fc
    const size_t fcn = (size_t)BD * TVD * FCD;   // elements
    const bool preconv = ((off + fcn / 2 + 64) * sizeof(float) <= ws_size);
    unsigned short* vidfc_bf = preconv ? (unsigned short*)alloc(fcn / 2) : nullptr;

    hipMemsetAsync(h_bf_a, 0, (size_t)BD * HD * sizeof(unsigned short), stream);
    hipMemsetAsync(c_st, 0, (size_t)BD * HD * sizeof(float), stream);
    hipMemsetAsync(cap_ha, 0, (size_t)BCD * HD * sizeof(float), stream);
    hipMemsetAsync(cap_cst, 0, (size_t)BCD * HD * sizeof(float), stream);

    // weight conversions
    conv_f2b_kernel<<<512, 256, 0, stream>>>(W_vemb, Wvemb_bf, VEMBD * FCD / 4);
    conv_f2b_kernel<<<128, 256, 0, stream>>>(W_vid, Wvid_bf, AD * HD / 4);
    conv_wcat_perm_kernel<<<2048, 256, 0, stream>>>(Wih_v, Whh_v, Wcat_bf);
    conv_bsum_kernel<<<8, 256, 0, stream>>>(bih_v, bhh_v, bsum);

    // caption front path (fp32)
    gemm_bias_kernel<<<dim3(WEMBD / 64, (BCD * TCD) / 64), 256, 0, stream>>>(
        video_caption, W_wemb, b_wemb, cap_x, BCD * TCD, WEMBD, GLOVED);
    gemm_bias_kernel<<<dim3((4 * HD) / 64, (BCD * TCD) / 64), 256, 0, stream>>>(
        cap_x, Wih_c, bih_c, xg_c, BCD * TCD, 4 * HD, WEMBD);

    // vid_x GEMM (bf16 MFMA, m-fastest grid); pre-convert A when ws allows
    if (preconv) {
        conv_f2b_kernel<<<2048, 256, 0, stream>>>(video_fc, vidfc_bf, (int)(fcn / 4));
        mfma_gemm128<0, 1><<<dim3((BD * TVD) / 128, VEMBD / 128), 256, 0, stream>>>(
            vidfc_bf, Wvemb_bf, b_vemb, vidx_bf, BD * TVD, VEMBD, FCD);
    } else {
        mfma_gemm128<1, 1><<<dim3((BD * TVD) / 128, VEMBD / 128), 256, 0, stream>>>(
            video_fc, Wvemb_bf, b_vemb, vidx_bf, BD * TVD, VEMBD, FCD);
    }

    // fused LSTM steps: vid blocks 0..1023 (4/CU), cap blocks 1024..1055 (t<20)
    for (int t = 0; t < TVD; t++) {
        const unsigned short* hin = (t & 1) ? h_bf_b : h_bf_a;
        unsigned short* hout = (t & 1) ? h_bf_a : h_bf_b;
        const float* chin = (t & 1) ? cap_hb : cap_ha;
        float* chout = (t & 1) ? cap_ha : cap_hb;
        const int nblk = (t < TCD) ? 1056 : 1024;
        step_fused<<<nblk, 256, 0, stream>>>(
            vidx_bf, hin, hout, Wcat_bf, bsum, c_st, vidh_bf, t,
            xg_c, Whh_c, bhh_c, chin, chout, cap_cst, cap_h);
    }

    // post GEMMs
    gemm_bias_kernel<<<dim3(AD / 64, (BCD * TCD) / 64), 256, 0, stream>>>(
        cap_h, W_sen, b_sen, c_lin, BCD * TCD, AD, HD);
    mfma_gemm128<0, 0><<<dim3((BD * TVD) / 128, AD / 128), 256, 0, stream>>>(
        vidh_bf, Wvid_bf, b_vid, v_lin, BD * TVD, AD, HD);

    // attention (+cap_ftr fused) + vid mean
    attn_kernel<<<BD, 256, 0, stream>>>(v_lin, c_lin, W_att, b_att, cap_len, cap_h, out2);
    vidmean_bf_kernel<<<(BD * HD / 8) / 256, 256, 0, stream>>>(vidh_bf, out1);
}

// Round 14
// 817.683 us; speedup vs baseline: 1.1923x; 1.1923x over previous
//
#include <hip/hip_runtime.h>
#include <hip/hip_bf16.h>

#define FCD 2048
#define VEMBD 512
#define WEMBD 512
#define HD 512
#define AD 256
#define TVD 32
#define TCD 20
#define BCD 16
#define RPD 32
#define BD 512     // BCD*RPD
#define GLOVED 300

typedef __attribute__((ext_vector_type(8))) short short8v;
typedef __attribute__((ext_vector_type(4))) float f32x4;

__device__ __forceinline__ float sigf(float x) { return 1.0f / (1.0f + __expf(-x)); }
__device__ __forceinline__ float tanhfast(float x) {
    float e = __expf(2.0f * x);
    return 1.0f - 2.0f / (e + 1.0f);
}
__device__ __forceinline__ unsigned short f2bf(float x) {
    union { __hip_bfloat16 h; unsigned short u; } v;
    v.h = __float2bfloat16(x);
    return v.u;
}
__device__ __forceinline__ float b2f(unsigned short u) {
    union { unsigned int i; float f; } v;
    v.i = ((unsigned int)u) << 16;
    return v.f;
}

// ---------------------------------------------------------------------------
// fp32 -> bf16 elementwise convert
// ---------------------------------------------------------------------------
__launch_bounds__(256)
__global__ void conv_f2b_kernel(const float* __restrict__ src,
                                unsigned short* __restrict__ dst, int n4) {
    for (int i = blockIdx.x * 256 + threadIdx.x; i < n4; i += gridDim.x * 256) {
        const float4 v = ((const float4*)src)[i];
        ushort4 o;
        o.x = f2bf(v.x); o.y = f2bf(v.y); o.z = f2bf(v.z); o.w = f2bf(v.w);
        ((ushort4*)dst)[i] = o;
    }
}

// Permuted+concatenated gate weights: Wcat[g'][0:512]=Wih[g], [512:1024]=Whh[g]
// g' = (hc>>4)*64 + q*16 + (hc&15), g = q*512 + hc. bf16 out.
__launch_bounds__(256)
__global__ void conv_wcat_perm_kernel(const float* __restrict__ Wih,
                                      const float* __restrict__ Whh,
                                      unsigned short* __restrict__ Wcat) {
    const int gp = blockIdx.x;
    const int q = (gp >> 4) & 3;
    const int hc = (gp >> 6) * 16 + (gp & 15);
    const long g = (long)(q * 512 + hc);
    for (int k = threadIdx.x; k < 512; k += 256) {
        Wcat[(long)gp * 1024 + k]       = f2bf(Wih[g * 512 + k]);
        Wcat[(long)gp * 1024 + 512 + k] = f2bf(Whh[g * 512 + k]);
    }
}

__launch_bounds__(256)
__global__ void conv_bsum_kernel(const float* __restrict__ bih,
                                 const float* __restrict__ bhh,
                                 float* __restrict__ bsum) {
    const int gp = blockIdx.x * 256 + threadIdx.x;
    if (gp < 2048) {
        const int q = (gp >> 4) & 3;
        const int hc = (gp >> 6) * 16 + (gp & 15);
        const int g = q * 512 + hc;
        bsum[gp] = bih[g] + bhh[g];
    }
}

// ---------------------------------------------------------------------------
// MFMA bf16 GEMM, 128x128 tile, BK=64, register-prefetch staging.
// Grid: x = m-tiles (fastest), y = n-tiles.
// ---------------------------------------------------------------------------
template<int AF32, int OBF>
__launch_bounds__(256)
__global__ void mfma_gemm128(const void* __restrict__ A,
                             const unsigned short* __restrict__ Bw,
                             const float* __restrict__ bias,
                             void* __restrict__ Cout,
                             int M, int N, int K)
{
    __shared__ unsigned short As[128][72];
    __shared__ unsigned short Bs[128][72];
    const int m0 = blockIdx.x * 128;
    const int n0 = blockIdx.y * 128;
    const int tid = threadIdx.x;
    const int lane = tid & 63;
    const int wid = tid >> 6;
    const int wm = (wid >> 1) * 64;
    const int wn = (wid & 1) * 64;
    const int lrow = lane & 15;
    const int lko = (lane >> 4) * 8;
    const int sr = tid >> 1;
    const int sc = (tid & 1) * 32;

    f32x4 acc[4][4] = {};

    const float* Arow_f = (const float*)A + (long)(m0 + sr) * K;
    const unsigned short* Arow_b = (const unsigned short*)A + (long)(m0 + sr) * K;
    const unsigned short* Brow = Bw + (long)(n0 + sr) * K;

    if (AF32) {
#pragma unroll
        for (int i = 0; i < 8; i++) {
            const float4 v = *(const float4*)(Arow_f + sc + i * 4);
            unsigned short* d = &As[sr][sc + i * 4];
            d[0] = f2bf(v.x); d[1] = f2bf(v.y); d[2] = f2bf(v.z); d[3] = f2bf(v.w);
        }
    } else {
#pragma unroll
        for (int i = 0; i < 4; i++)
            *(short8v*)&As[sr][sc + i * 8] = *(const short8v*)(Arow_b + sc + i * 8);
    }
#pragma unroll
    for (int i = 0; i < 4; i++)
        *(short8v*)&Bs[sr][sc + i * 8] = *(const short8v*)(Brow + sc + i * 8);
    __syncthreads();

    const int nc = K >> 6;
    float4 paf[8];
    short8v pab[4], pb[4];
    for (int c = 0; c < nc; c++) {
        if (c < nc - 1) {
            const int k0 = (c + 1) * 64;
            if (AF32) {
#pragma unroll
                for (int i = 0; i < 8; i++)
                    paf[i] = *(const float4*)(Arow_f + k0 + sc + i * 4);
            } else {
#pragma unroll
                for (int i = 0; i < 4; i++)
                    pab[i] = *(const short8v*)(Arow_b + k0 + sc + i * 8);
            }
#pragma unroll
            for (int i = 0; i < 4; i++)
                pb[i] = *(const short8v*)(Brow + k0 + sc + i * 8);
        }
#pragma unroll
        for (int kk = 0; kk < 2; kk++) {
            short8v a[4], b[4];
#pragma unroll
            for (int mi = 0; mi < 4; mi++)
                a[mi] = *(const short8v*)&As[wm + mi * 16 + lrow][kk * 32 + lko];
#pragma unroll
            for (int ni = 0; ni < 4; ni++)
                b[ni] = *(const short8v*)&Bs[wn + ni * 16 + lrow][kk * 32 + lko];
#pragma unroll
            for (int mi = 0; mi < 4; mi++)
#pragma unroll
                for (int ni = 0; ni < 4; ni++)
                    acc[mi][ni] = __builtin_amdgcn_mfma_f32_16x16x32_bf16(
                        a[mi], b[ni], acc[mi][ni], 0, 0, 0);
        }
        __syncthreads();
        if (c < nc - 1) {
            if (AF32) {
#pragma unroll
                for (int i = 0; i < 8; i++) {
                    unsigned short* d = &As[sr][sc + i * 4];
                    d[0] = f2bf(paf[i].x); d[1] = f2bf(paf[i].y);
                    d[2] = f2bf(paf[i].z); d[3] = f2bf(paf[i].w);
                }
            } else {
#pragma unroll
                for (int i = 0; i < 4; i++)
                    *(short8v*)&As[sr][sc + i * 8] = pab[i];
            }
#pragma unroll
            for (int i = 0; i < 4; i++)
                *(short8v*)&Bs[sr][sc + i * 8] = pb[i];
            __syncthreads();
        }
    }

    const int rbase = (lane >> 4) * 4;
#pragma unroll
    for (int ni = 0; ni < 4; ni++) {
        const int col = n0 + wn + ni * 16 + lrow;
        const float bv = bias[col];
#pragma unroll
        for (int mi = 0; mi < 4; mi++) {
#pragma unroll
            for (int j = 0; j < 4; j++) {
                const long row = m0 + wm + mi * 16 + rbase + j;
                const float val = acc[mi][ni][j] + bv;
                if (OBF) ((unsigned short*)Cout)[row * N + col] = f2bf(val);
                else     ((float*)Cout)[row * N + col] = val;
            }
        }
    }
}

// ---------------------------------------------------------------------------
// Fused LSTM step (R8-proven body), 256 threads, 26.1 KB LDS, 2 blocks/CU.
// Blocks 0..511: vid step, tile = 32 batch x 64 g'. BK=128 (8 chunks),
//   1-deep register prefetch. Wave w: gate-pair nq=w>>1 for batch-half
//   bi=w&1; waves 2,3 hand q2,q3 via 4 KB LDS exchange.
// Blocks 512..543 (t<TC): caption fp32 step.
// ---------------------------------------------------------------------------
__launch_bounds__(256, 2)
__global__ void step_fused(const unsigned short* __restrict__ vx,   // [B*TV][512] bf16
                           const unsigned short* __restrict__ h_in, // [B][512] bf16
                           unsigned short* __restrict__ h_out,      // [B][512] bf16
                           const unsigned short* __restrict__ Wcat, // [2048][1024] bf16
                           const float* __restrict__ bsum,          // [2048]
                           float* __restrict__ c_state,             // [B][512] f32
                           unsigned short* __restrict__ vid_h,      // [B*TV][512] bf16
                           int t,
                           const float* __restrict__ xg,            // cap
                           const float* __restrict__ Whh_c,
                           const float* __restrict__ bhh_c,
                           const float* __restrict__ hc_in,
                           float* __restrict__ hc_out,
                           float* __restrict__ cap_cst,
                           float* __restrict__ cap_h)
{
    __shared__ __align__(16) unsigned char smem[26112];
    const int bx = blockIdx.x;
    const int tid = threadIdx.x;

    if (bx >= 512) {
        // ---------------- caption step (fp32, 256 threads) ----------------
        const int h0 = (bx - 512) * 16;
        float* Wsc = (float*)smem;              // [64][68]
        float* Hshc = (float*)(smem + 17408);   // [16][68]
        const int tx = tid & 15;
        const int ty = tid >> 4;
        const int lrow2 = tid >> 2;
        const int lq = tid & 3;
        float acc4[4] = {};

        for (int k0 = 0; k0 < 512; k0 += 64) {
            {
                const int q = lrow2 >> 4;
                const int hcc = lrow2 & 15;
                const float* src = Whh_c + (long)(q * 512 + h0 + hcc) * 512 + k0 + lq * 16;
                const int col = hcc * 4 + q;
#pragma unroll
                for (int j = 0; j < 4; j++) {
                    const float4 v = *(const float4*)(src + j * 4);
                    Wsc[(lq * 16 + j * 4 + 0) * 68 + col] = v.x;
                    Wsc[(lq * 16 + j * 4 + 1) * 68 + col] = v.y;
                    Wsc[(lq * 16 + j * 4 + 2) * 68 + col] = v.z;
                    Wsc[(lq * 16 + j * 4 + 3) * 68 + col] = v.w;
                }
            }
            {
                const int lb = tid >> 4;
                const int lk4 = (tid & 15) * 4;
                *(float4*)&Hshc[lb * 68 + lk4] = *(const float4*)(hc_in + (long)lb * 512 + k0 + lk4);
            }
            __syncthreads();
#pragma unroll
            for (int kq = 0; kq < 16; kq++) {
                const float4 h4 = *(const float4*)&Hshc[ty * 68 + kq * 4];
                const float4 w0 = *(const float4*)&Wsc[(kq * 4 + 0) * 68 + tx * 4];
                const float4 w1 = *(const float4*)&Wsc[(kq * 4 + 1) * 68 + tx * 4];
                const float4 w2 = *(const float4*)&Wsc[(kq * 4 + 2) * 68 + tx * 4];
                const float4 w3 = *(const float4*)&Wsc[(kq * 4 + 3) * 68 + tx * 4];
                acc4[0] += h4.x * w0.x + h4.y * w1.x + h4.z * w2.x + h4.w * w3.x;
                acc4[1] += h4.x * w0.y + h4.y * w1.y + h4.z * w2.y + h4.w * w3.y;
                acc4[2] += h4.x * w0.z + h4.y * w1.z + h4.z * w2.z + h4.w * w3.z;
                acc4[3] += h4.x * w0.w + h4.y * w1.w + h4.z * w2.w + h4.w * w3.w;
            }
            __syncthreads();
        }
        const int hc = h0 + tx;
        const long xrow = (long)(ty * TCD + t) * 2048;
        const float gi = acc4[0] + xg[xrow + hc]        + bhh_c[hc];
        const float gf = acc4[1] + xg[xrow + 512 + hc]  + bhh_c[512 + hc];
        const float gg = acc4[2] + xg[xrow + 1024 + hc] + bhh_c[1024 + hc];
        const float go = acc4[3] + xg[xrow + 1536 + hc] + bhh_c[1536 + hc];
        const float c_old = cap_cst[(long)ty * 512 + hc];
        const float ii = sigf(gi), ff = sigf(gf), g2 = tanhfast(gg), oo = sigf(go);
        const float c = ff * c_old + ii * g2;
        const float h = oo * tanhfast(c);
        cap_cst[(long)ty * 512 + hc] = c;
        hc_out[(long)ty * 512 + hc] = h;
        cap_h[(long)(ty * TCD + t) * 512 + hc] = h;
        return;
    }

    // ---------------- video step (BK=128, 8 chunks) ----------------
    const int n0 = (bx & 31) * 64;    // g' base
    const int b0 = (bx >> 5) * 32;    // batch base
    const int lane = tid & 63;
    const int w = tid >> 6;           // wave 0..3
    const int bi = w & 1;             // batch half
    const int nq = w >> 1;            // gate-pair
    const int lrow = lane & 15;
    const int lko = (lane >> 4) * 8;
    const int sra = tid >> 3;         // A staging row 0..31
    const int sca = (tid & 7) * 16;   // staging col base

    unsigned short* As = (unsigned short*)smem;           // [32][136] = 8704 B
    unsigned short* Ws = (unsigned short*)(smem + 8704);  // [64][136] = 17408 B

    const unsigned short* arow_vx = vx + ((long)(b0 + sra) * TVD + t) * 512;
    const unsigned short* arow_h  = h_in + (long)(b0 + sra) * 512;
    const unsigned short* wrow0   = Wcat + (long)(n0 + sra) * 1024;
    const unsigned short* wrow1   = Wcat + (long)(n0 + sra + 32) * 1024;

    f32x4 acc[2] = {};

    // stage chunk 0 (k 0..127, vx side)
    *(short8v*)&As[sra * 136 + sca]     = *(const short8v*)(arow_vx + sca);
    *(short8v*)&As[sra * 136 + sca + 8] = *(const short8v*)(arow_vx + sca + 8);
    *(short8v*)&Ws[sra * 136 + sca]            = *(const short8v*)(wrow0 + sca);
    *(short8v*)&Ws[sra * 136 + sca + 8]        = *(const short8v*)(wrow0 + sca + 8);
    *(short8v*)&Ws[(sra + 32) * 136 + sca]     = *(const short8v*)(wrow1 + sca);
    *(short8v*)&Ws[(sra + 32) * 136 + sca + 8] = *(const short8v*)(wrow1 + sca + 8);
    __syncthreads();

    short8v pa0, pa1, pw0, pw1, pw2, pw3;
    for (int c = 0; c < 8; c++) {
        if (c < 7) {
            const int k0 = (c + 1) * 128;
            const unsigned short* ap = (k0 < 512) ? (arow_vx + k0) : (arow_h + (k0 - 512));
            pa0 = *(const short8v*)(ap + sca);
            pa1 = *(const short8v*)(ap + sca + 8);
            pw0 = *(const short8v*)(wrow0 + k0 + sca);
            pw1 = *(const short8v*)(wrow0 + k0 + sca + 8);
            pw2 = *(const short8v*)(wrow1 + k0 + sca);
            pw3 = *(const short8v*)(wrow1 + k0 + sca + 8);
        }
#pragma unroll
        for (int kk = 0; kk < 4; kk++) {
            const short8v a = *(const short8v*)&As[(bi * 16 + lrow) * 136 + kk * 32 + lko];
#pragma unroll
            for (int nl = 0; nl < 2; nl++) {
                const short8v b = *(const short8v*)&Ws[((nq * 2 + nl) * 16 + lrow) * 136 + kk * 32 + lko];
                acc[nl] = __builtin_amdgcn_mfma_f32_16x16x32_bf16(a, b, acc[nl], 0, 0, 0);
            }
        }
        __syncthreads();
        if (c < 7) {
            *(short8v*)&As[sra * 136 + sca]            = pa0;
            *(short8v*)&As[sra * 136 + sca + 8]        = pa1;
            *(short8v*)&Ws[sra * 136 + sca]            = pw0;
            *(short8v*)&Ws[sra * 136 + sca + 8]        = pw1;
            *(short8v*)&Ws[(sra + 32) * 136 + sca]     = pw2;
            *(short8v*)&Ws[(sra + 32) * 136 + sca + 8] = pw3;
            __syncthreads();
        }
    }

    // gate exchange: waves 2,3 (q2,q3) -> LDS; waves 0,1 do cell update
    float* red = (float*)smem;   // [2][32][16] f32 = 4 KB (As region, done)
    const int rbase = (lane >> 4) * 4;
    if (w >= 2) {
#pragma unroll
        for (int nl = 0; nl < 2; nl++)
#pragma unroll
            for (int j = 0; j < 4; j++)
                red[nl * 512 + (bi * 16 + rbase + j) * 16 + lrow] = acc[nl][j];
    }
    __syncthreads();
    if (w < 2) {
        const int hc = (n0 >> 2) + lrow;
        const float bs0 = bsum[n0 + lrow];
        const float bs1 = bsum[n0 + 16 + lrow];
        const float bs2 = bsum[n0 + 32 + lrow];
        const float bs3 = bsum[n0 + 48 + lrow];
#pragma unroll
        for (int j = 0; j < 4; j++) {
            const int blocal = bi * 16 + rbase + j;
            const long b = b0 + blocal;
            const float gi = acc[0][j] + bs0;
            const float gf = acc[1][j] + bs1;
            const float gg = red[blocal * 16 + lrow] + bs2;
            const float go = red[512 + blocal * 16 + lrow] + bs3;
            const float c_old = c_state[b * 512 + hc];
            const float ii = sigf(gi), ff = sigf(gf), g2 = tanhfast(gg), oo = sigf(go);
            const float cn = ff * c_old + ii * g2;
            const float h = oo * tanhfast(cn);
            c_state[b * 512 + hc] = cn;
            h_out[b * 512 + hc] = f2bf(h);
            vid_h[(b * TVD + t) * 512 + hc] = f2bf(h);
        }
    }
}

// ---------------------------------------------------------------------------
// Generic fp32 tiled GEMM (cap front path + c_lin)
// ---------------------------------------------------------------------------
__launch_bounds__(256)
__global__ void gemm_bias_kernel(const float* __restrict__ A,
                                 const float* __restrict__ Bw,
                                 const float* __restrict__ bias,
                                 float* __restrict__ C,
                                 int M, int N, int K) {
    __shared__ float As[16][68];
    __shared__ float Bs[16][68];
    const int n0 = blockIdx.x * 64;
    const int m0 = blockIdx.y * 64;
    const int tid = threadIdx.x;
    const int tx = tid & 15;
    const int ty = tid >> 4;
    const int lrow = tid >> 2;
    const int lk4 = (tid & 3) * 4;

    float acc[4][4] = {};

    for (int k0 = 0; k0 < K; k0 += 16) {
        {
            const float* src = A + (long)(m0 + lrow) * K + k0 + lk4;
            float4 v;
            if (k0 + 16 <= K) v = *(const float4*)src;
            else {
                v.x = (k0 + lk4 + 0 < K) ? src[0] : 0.f;
                v.y = (k0 + lk4 + 1 < K) ? src[1] : 0.f;
                v.z = (k0 + lk4 + 2 < K) ? src[2] : 0.f;
                v.w = (k0 + lk4 + 3 < K) ? src[3] : 0.f;
            }
            As[lk4 + 0][lrow] = v.x; As[lk4 + 1][lrow] = v.y;
            As[lk4 + 2][lrow] = v.z; As[lk4 + 3][lrow] = v.w;
        }
        {
            const float* src = Bw + (long)(n0 + lrow) * K + k0 + lk4;
            float4 v;
            if (k0 + 16 <= K) v = *(const float4*)src;
            else {
                v.x = (k0 + lk4 + 0 < K) ? src[0] : 0.f;
                v.y = (k0 + lk4 + 1 < K) ? src[1] : 0.f;
                v.z = (k0 + lk4 + 2 < K) ? src[2] : 0.f;
                v.w = (k0 + lk4 + 3 < K) ? src[3] : 0.f;
            }
            Bs[lk4 + 0][lrow] = v.x; Bs[lk4 + 1][lrow] = v.y;
            Bs[lk4 + 2][lrow] = v.z; Bs[lk4 + 3][lrow] = v.w;
        }
        __syncthreads();
#pragma unroll
        for (int kk = 0; kk < 16; kk++) {
            const float4 av = *(const float4*)&As[kk][ty * 4];
            const float4 bv = *(const float4*)&Bs[kk][tx * 4];
            acc[0][0] += av.x * bv.x; acc[0][1] += av.x * bv.y; acc[0][2] += av.x * bv.z; acc[0][3] += av.x * bv.w;
            acc[1][0] += av.y * bv.x; acc[1][1] += av.y * bv.y; acc[1][2] += av.y * bv.z; acc[1][3] += av.y * bv.w;
            acc[2][0] += av.z * bv.x; acc[2][1] += av.z * bv.y; acc[2][2] += av.z * bv.z; acc[2][3] += av.z * bv.w;
            acc[3][0] += av.w * bv.x; acc[3][1] += av.w * bv.y; acc[3][2] += av.w * bv.z; acc[3][3] += av.w * bv.w;
        }
        __syncthreads();
    }

    const float b0v = bias[n0 + tx * 4 + 0];
    const float b1v = bias[n0 + tx * 4 + 1];
    const float b2v = bias[n0 + tx * 4 + 2];
    const float b3v = bias[n0 + tx * 4 + 3];
#pragma unroll
    for (int i = 0; i < 4; i++) {
        float* dst = C + (long)(m0 + ty * 4 + i) * N + n0 + tx * 4;
        dst[0] = acc[i][0] + b0v;
        dst[1] = acc[i][1] + b1v;
        dst[2] = acc[i][2] + b2v;
        dst[3] = acc[i][3] + b3v;
    }
}

// ---------------------------------------------------------------------------
// Attention + cap_ftr fused, shuffle-free: one block per (bc,rp).
// ---------------------------------------------------------------------------
#define PFL 258
__launch_bounds__(256, 2)
__global__ void attn_kernel(const float* __restrict__ v_lin,
                            const float* __restrict__ c_lin,
                            const float* __restrict__ W_att,
                            const float* __restrict__ b_att,
                            const int* __restrict__ cap_len,
                            const float* __restrict__ cap_h,
                            float* __restrict__ out2)
{
    const int br = blockIdx.x;
    const int bc = br >> 5;
    const int tid = threadIdx.x;
    __shared__ float cl[TCD][PFL];
    __shared__ float vl[TVD][PFL];
    __shared__ float wa[AD];
    __shared__ float sl[TVD][TCD];
    __shared__ float wsum[TCD];

    {
        const float* csrc = c_lin + (long)bc * TCD * AD;
        for (int idx = tid; idx < TCD * 128; idx += 256) {
            const int row = idx >> 7, c2 = (idx & 127) * 2;
            *(float2*)&cl[row][c2] = *(const float2*)(csrc + row * AD + c2);
        }
        const float* vsrc = v_lin + (long)br * TVD * AD;
        for (int idx = tid; idx < TVD * 128; idx += 256) {
            const int row = idx >> 7, c2 = (idx & 127) * 2;
            *(float2*)&vl[row][c2] = *(const float2*)(vsrc + row * AD + c2);
        }
        wa[tid] = W_att[tid];
    }
    const float batt = b_att[0];
    __syncthreads();

    {
        const int v = tid & 31;
        const int tg = tid >> 5;        // 0..7
        const int t0 = tg, t1 = tg + 8, t2 = tg + 16;
        const bool ok2 = (t2 < TCD);
        const int t2c = ok2 ? t2 : 0;
        float s0 = 0.f, s1 = 0.f, s2 = 0.f;
#pragma unroll 4
        for (int i = 0; i < 128; i++) {
            const float2 w2 = *(const float2*)&wa[2 * i];
            const float2 vv = *(const float2*)&vl[v][2 * i];
            const float2 c0 = *(const float2*)&cl[t0][2 * i];
            const float2 c1 = *(const float2*)&cl[t1][2 * i];
            const float2 c2 = *(const float2*)&cl[t2c][2 * i];
            s0 += tanhfast(vv.x + c0.x) * w2.x + tanhfast(vv.y + c0.y) * w2.y;
            s1 += tanhfast(vv.x + c1.x) * w2.x + tanhfast(vv.y + c1.y) * w2.y;
            s2 += tanhfast(vv.x + c2.x) * w2.x + tanhfast(vv.y + c2.y) * w2.y;
        }
        sl[v][t0] = s0 + batt;
        sl[v][t1] = s1 + batt;
        if (ok2) sl[v][t2] = s2 + batt;
    }
    __syncthreads();

    int L = cap_len[bc];
    if (L < 1) L = 1;
    if (tid < TVD) {
        const int v = tid;
        float m = -1e30f;
        for (int t = 0; t < TCD; t++)
            if (t < L) m = fmaxf(m, sl[v][t]);
        float sum = 0.f;
        for (int t = 0; t < TCD; t++)
            if (t < L) sum += __expf(sl[v][t] - m);
        const float inv = 1.f / sum;
        for (int t = 0; t < TCD; t++)
            sl[v][t] = (t < L) ? __expf(sl[v][t] - m) * inv : 0.f;
    }
    __syncthreads();
    if (tid < TCD) {
        float s = 0.f;
        for (int v = 0; v < TVD; v++) s += sl[v][tid];
        wsum[tid] = s * (1.0f / TVD);
    }
    __syncthreads();

    const float* chb = cap_h + (long)bc * TCD * HD;
#pragma unroll
    for (int r = 0; r < 2; r++) {
        const int h = r * 256 + tid;
        float s = 0.f;
#pragma unroll
        for (int t = 0; t < TCD; t++)
            s += wsum[t] * chb[t * HD + h];
        out2[(long)br * HD + h] = s;
    }
}

// vid_mean from bf16 vid_h
__launch_bounds__(256)
__global__ void vidmean_bf_kernel(const unsigned short* __restrict__ vid_h,
                                  float* __restrict__ out1)
{
    const int idx = blockIdx.x * 256 + threadIdx.x;   // 0..32767
    const int b = idx >> 6;
    const int h8 = (idx & 63) * 8;
    float s[8] = {};
    for (int t = 0; t < TVD; t++) {
        const short8v v = *(const short8v*)(vid_h + ((long)b * TVD + t) * 512 + h8);
#pragma unroll
        for (int j = 0; j < 8; j++) s[j] += b2f((unsigned short)v[j]);
    }
#pragma unroll
    for (int j = 0; j < 8; j++)
        out1[(long)b * 512 + h8 + j] = s[j] * (1.0f / TVD);
}

extern "C" void kernel_launch(void* const* d_in, const int* in_sizes, int n_in,
                              void* d_out, int out_size, void* d_ws, size_t ws_size,
                              hipStream_t stream) {
    const float* video_fc      = (const float*)d_in[0];
    const float* video_caption = (const float*)d_in[1];
    const int*   cap_len       = (const int*)d_in[2];
    const float* W_vemb = (const float*)d_in[3];
    const float* b_vemb = (const float*)d_in[4];
    const float* W_wemb = (const float*)d_in[5];
    const float* b_wemb = (const float*)d_in[6];
    const float* Wih_v  = (const float*)d_in[7];
    const float* Whh_v  = (const float*)d_in[8];
    const float* bih_v  = (const float*)d_in[9];
    const float* bhh_v  = (const float*)d_in[10];
    const float* Wih_c  = (const float*)d_in[11];
    const float* Whh_c  = (const float*)d_in[12];
    const float* bih_c  = (const float*)d_in[13];
    const float* bhh_c  = (const float*)d_in[14];
    const float* W_vid  = (const float*)d_in[15];
    const float* b_vid  = (const float*)d_in[16];
    const float* W_sen  = (const float*)d_in[17];
    const float* b_sen  = (const float*)d_in[18];
    const float* W_att  = (const float*)d_in[19];
    const float* b_att  = (const float*)d_in[20];

    float* out1 = (float*)d_out;            // vid_mean
    float* out2 = out1 + BD * HD;           // cap_ftr_mean

    float* ws = (float*)d_ws;
    size_t off = 0;
    auto alloc = [&](size_t nfloats) {
        float* p = ws + off;
        off += (nfloats + 63) & ~(size_t)63;
        return p;
    };
    unsigned short* vidx_bf = (unsigned short*)alloc((size_t)BD * TVD * VEMBD / 2);
    unsigned short* vidh_bf = (unsigned short*)alloc((size_t)BD * TVD * HD / 2);
    unsigned short* h_bf_a  = (unsigned short*)alloc((size_t)BD * HD / 2);
    unsigned short* h_bf_b  = (unsigned short*)alloc((size_t)BD * HD / 2);
    float* c_st    = alloc((size_t)BD * HD);
    float* v_lin   = alloc((size_t)BD * TVD * AD);
    unsigned short* Wvemb_bf = (unsigned short*)alloc((size_t)VEMBD * FCD / 2);
    unsigned short* Wvid_bf  = (unsigned short*)alloc((size_t)AD * HD / 2);
    unsigned short* Wcat_bf  = (unsigned short*)alloc((size_t)2048 * 1024 / 2);
    float* bsum    = alloc(2048);
    float* cap_x   = alloc((size_t)BCD * TCD * WEMBD);
    float* xg_c    = alloc((size_t)BCD * TCD * 4 * HD);
    float* cap_h   = alloc((size_t)BCD * TCD * HD);
    float* c_lin   = alloc((size_t)BCD * TCD * AD);
    float* cap_ha  = alloc((size_t)BCD * HD);
    float* cap_hb  = alloc((size_t)BCD * HD);
    float* cap_cst = alloc((size_t)BCD * HD);
    // big optional buffer last: bf16 copy of video_fc
    const size_t fcn = (size_t)BD * TVD * FCD;   // elements
    const bool preconv = ((off + fcn / 2 + 64) * sizeof(float) <= ws_size);
    unsigned short* vidfc_bf = preconv ? (unsigned short*)alloc(fcn / 2) : nullptr;

    hipMemsetAsync(h_bf_a, 0, (size_t)BD * HD * sizeof(unsigned short), stream);
    hipMemsetAsync(c_st, 0, (size_t)BD * HD * sizeof(float), stream);
    hipMemsetAsync(cap_ha, 0, (size_t)BCD * HD * sizeof(float), stream);
    hipMemsetAsync(cap_cst, 0, (size_t)BCD * HD * sizeof(float), stream);

    // weight conversions
    conv_f2b_kernel<<<512, 256, 0, stream>>>(W_vemb, Wvemb_bf, VEMBD * FCD / 4);
    conv_f2b_kernel<<<128, 256, 0, stream>>>(W_vid, Wvid_bf, AD * HD / 4);
    conv_wcat_perm_kernel<<<2048, 256, 0, stream>>>(Wih_v, Whh_v, Wcat_bf);
    conv_bsum_kernel<<<8, 256, 0, stream>>>(bih_v, bhh_v, bsum);

    // caption front path (fp32)
    gemm_bias_kernel<<<dim3(WEMBD / 64, (BCD * TCD) / 64), 256, 0, stream>>>(
        video_caption, W_wemb, b_wemb, cap_x, BCD * TCD, WEMBD, GLOVED);
    gemm_bias_kernel<<<dim3((4 * HD) / 64, (BCD * TCD) / 64), 256, 0, stream>>>(
        cap_x, Wih_c, bih_c, xg_c, BCD * TCD, 4 * HD, WEMBD);

    // vid_x GEMM (bf16 MFMA, m-fastest grid); pre-convert A when ws allows
    if (preconv) {
        conv_f2b_kernel<<<2048, 256, 0, stream>>>(video_fc, vidfc_bf, (int)(fcn / 4));
        mfma_gemm128<0, 1><<<dim3((BD * TVD) / 128, VEMBD / 128), 256, 0, stream>>>(
            vidfc_bf, Wvemb_bf, b_vemb, vidx_bf, BD * TVD, VEMBD, FCD);
    } else {
        mfma_gemm128<1, 1><<<dim3((BD * TVD) / 128, VEMBD / 128), 256, 0, stream>>>(
            video_fc, Wvemb_bf, b_vemb, vidx_bf, BD * TVD, VEMBD, FCD);
    }

    // fused LSTM steps: vid blocks 0..511 (2/CU), cap blocks 512..543 (t<20)
    for (int t = 0; t < TVD; t++) {
        const unsigned short* hin = (t & 1) ? h_bf_b : h_bf_a;
        unsigned short* hout = (t & 1) ? h_bf_a : h_bf_b;
        const float* chin = (t & 1) ? cap_hb : cap_ha;
        float* chout = (t & 1) ? cap_ha : cap_hb;
        const int nblk = (t < TCD) ? 544 : 512;
        step_fused<<<nblk, 256, 0, stream>>>(
            vidx_bf, hin, hout, Wcat_bf, bsum, c_st, vidh_bf, t,
            xg_c, Whh_c, bhh_c, chin, chout, cap_cst, cap_h);
    }

    // post GEMMs
    gemm_bias_kernel<<<dim3(AD / 64, (BCD * TCD) / 64), 256, 0, stream>>>(
        cap_h, W_sen, b_sen, c_lin, BCD * TCD, AD, HD);
    mfma_gemm128<0, 0><<<dim3((BD * TVD) / 128, AD / 128), 256, 0, stream>>>(
        vidh_bf, Wvid_bf, b_vid, v_lin, BD * TVD, AD, HD);

    // attention (+cap_ftr fused) + vid mean
    attn_kernel<<<BD, 256, 0, stream>>>(v_lin, c_lin, W_att, b_att, cap_len, cap_h, out2);
    vidmean_bf_kernel<<<(BD * HD / 8) / 256, 256, 0, stream>>>(vidh_bf, out1);
}